// Round 9
// baseline (269.205 us; speedup 1.0000x reference)
//
#include <hip/hip_runtime.h>

// ---------------------------------------------------------------------------
// qkv = x@W_attn; RoPE(q,k); flash-attn; y@W_proj
// B=2, T=2048, C=1024, H=16, HD=64.  I/O fp32; internal tensors bf16.
//
// R20 (R18 measured 259.08us; attn 44.2us x2 with MfmaUtil 6.8 / VALU 22.8 /
// HBM 3% -> the 2-barrier-per-tile vmcnt(0) drain is the remaining stall):
//  * T3-minimum 2-phase ping-pong (guide §5.5 recipe, m230-verified) applied
//    to attn_k, gemm1_qkv_k, gemm2_proj_k: LDS double-buffered; tile t+1's
//    global_load_lds issued into buf^1 BEFORE computing tile t from buf;
//    ONE barrier per tile (drains the prefetch after a full compute phase of
//    latency cover).  Buffer index is LDS address arithmetic (no VGPR cost).
//  * all frag/softmax/mask/epilogue math byte-identical to measured R18.
//  * rope/tp/cvt/trig and launch bookkeeping unchanged.
// ---------------------------------------------------------------------------

typedef __attribute__((ext_vector_type(8))) short short8;   // 8 bf16 = 4 VGPRs
typedef __attribute__((ext_vector_type(4))) float floatx4;  // MFMA C/D frag

__device__ __forceinline__ ushort f2bf(float f) {
    unsigned x = __float_as_uint(f);
    x += 0x7fffu + ((x >> 16) & 1u);   // round-to-nearest-even
    return (ushort)(x >> 16);
}
__device__ __forceinline__ float bf2f(ushort u) {
    return __uint_as_float(((unsigned)u) << 16);
}

#define MFMA16(a, b, c) __builtin_amdgcn_mfma_f32_16x16x32_bf16((a), (b), (c), 0, 0, 0)

// async global->LDS, 16 bytes per lane.  LDS dest must be wave-uniform base;
// HW writes base + lane*16.  Global src is per-lane.
__device__ __forceinline__ void glds16(const ushort* g, ushort* l) {
    __builtin_amdgcn_global_load_lds(
        (const __attribute__((address_space(1))) unsigned int*)g,
        (__attribute__((address_space(3))) unsigned int*)l, 16, 0, 0);
}

// ---------------------------------------------------------------------------
// Transpose + cvt: src f32 [R][C] -> dst bf16 [C][R].  32x32 tiles via LDS.
// ---------------------------------------------------------------------------
__global__ __launch_bounds__(256) void tp_k(const float* __restrict__ src,
                                            ushort* __restrict__ dst,
                                            int R, int C) {
    __shared__ ushort t[32][34];
    const int c0 = blockIdx.x * 32, r0 = blockIdx.y * 32;
    const int tr = threadIdx.x >> 5, tc = threadIdx.x & 31;
#pragma unroll
    for (int j = 0; j < 4; j++)
        t[tr + j * 8][tc] = f2bf(src[(size_t)(r0 + tr + j * 8) * C + c0 + tc]);
    __syncthreads();
#pragma unroll
    for (int j = 0; j < 4; j++)
        dst[(size_t)(c0 + tr + j * 8) * R + r0 + tc] = t[tc][tr + j * 8];
}

// ---------------------------------------------------------------------------
// cvt: f32 -> bf16, 4 elems/thread.
// ---------------------------------------------------------------------------
__global__ __launch_bounds__(256) void cvt_k(const float* __restrict__ src,
                                             ushort* __restrict__ dst) {
    const size_t i = ((size_t)blockIdx.x * 256 + threadIdx.x) * 4;
    float4 t4 = *(const float4*)&src[i];
    *(ushort4*)&dst[i] = make_ushort4(f2bf(t4.x), f2bf(t4.y), f2bf(t4.z), f2bf(t4.w));
}

// ---------------------------------------------------------------------------
// trig table: tab[t][j] = (cos(t * 10000^(-j/32)), sin(...)), f64 math
// identical to the original in-rope computation (bit-identical results).
// ---------------------------------------------------------------------------
__global__ __launch_bounds__(256) void trig_k(float2* __restrict__ tab) {
    const int idx = blockIdx.x * 256 + threadIdx.x;   // [0, 65536)
    const int t = idx >> 5, j = idx & 31;
    const double inv = pow(10000.0, -(double)j / 32.0);
    const double ang = (double)t * inv;
    tab[idx] = make_float2((float)cos(ang), (float)sin(ang));
}

// ---------------------------------------------------------------------------
// GEMM1 (one batch): qkv = xb[2048][1024](bf16) @ WaT^T (Bt bf16 [3072][1024])
//   -> q: [H,T,HD]  k: [H,T,HD]  v^T: [H,HD,T]  (bf16)
// R15 structure; R20: double-buffered staging, one barrier per K-step.
// ---------------------------------------------------------------------------
__global__ __launch_bounds__(256, 3) void gemm1_qkv_k(const ushort* __restrict__ Ab,
                                                      const ushort* __restrict__ Bt,
                                                      ushort* __restrict__ qb,
                                                      ushort* __restrict__ kb,
                                                      ushort* __restrict__ vtb) {
    __shared__ __align__(16) ushort As[2][128 * 64];  // 32 KB ping-pong
    __shared__ __align__(16) ushort Bs[2][64 * 64];   // 16 KB ping-pong
    const int tid = threadIdx.x;
    const int m0 = blockIdx.y * 128, n0 = blockIdx.x * 64;
    const int w = tid >> 6, lane = tid & 63, quad = lane >> 4, l16 = lane & 15;
    const int wr = w >> 1, wc = w & 1;
    const int K = 1024;
    const int srow = lane >> 3, sslot = lane & 7;  // staging sub-row / slot

    floatx4 acc[4][2];
#pragma unroll
    for (int mt = 0; mt < 4; mt++)
#pragma unroll
        for (int nt = 0; nt < 2; nt++) acc[mt][nt] = (floatx4){0.f, 0.f, 0.f, 0.f};

    // prologue: stage k0=0 into buf 0
#pragma unroll
    for (int jj = 0; jj < 4; jj++) {
        const int reg = jj * 4 + w;
        const int row = reg * 8 + srow;
        const int cs = sslot ^ (row & 7);
        glds16(&Ab[(size_t)(m0 + row) * K + cs * 8], &As[0][reg * 512]);
    }
#pragma unroll
    for (int jj = 0; jj < 2; jj++) {
        const int reg = jj * 4 + w;
        const int row = reg * 8 + srow;
        const int cs = sslot ^ (row & 7);
        glds16(&Bt[(size_t)(n0 + row) * K + cs * 8], &Bs[0][reg * 512]);
    }
    __syncthreads();   // vmcnt(0) drained -> buf0 ready

    for (int k0 = 0; k0 < K; k0 += 64) {
        const int cur = (k0 >> 6) & 1;
        // issue next K-step's loads into the other buffer (latency hides
        // under this K-step's ds_read+MFMA; drained at the end barrier).
        if (k0 + 64 < K) {
            const int kn = k0 + 64;
#pragma unroll
            for (int jj = 0; jj < 4; jj++) {
                const int reg = jj * 4 + w;
                const int row = reg * 8 + srow;
                const int cs = sslot ^ (row & 7);
                glds16(&Ab[(size_t)(m0 + row) * K + kn + cs * 8], &As[cur ^ 1][reg * 512]);
            }
#pragma unroll
            for (int jj = 0; jj < 2; jj++) {
                const int reg = jj * 4 + w;
                const int row = reg * 8 + srow;
                const int cs = sslot ^ (row & 7);
                glds16(&Bt[(size_t)(n0 + row) * K + kn + cs * 8], &Bs[cur ^ 1][reg * 512]);
            }
        }

#pragma unroll
        for (int kk = 0; kk < 2; kk++) {
            short8 af[4], bfr[2];
#pragma unroll
            for (int mt = 0; mt < 4; mt++) {
                const int row = wr * 64 + mt * 16 + l16;
                const int slot = ((kk << 2) | quad) ^ (row & 7);
                af[mt] = *(short8*)&As[cur][row * 64 + slot * 8];
            }
#pragma unroll
            for (int nt = 0; nt < 2; nt++) {
                const int row = wc * 32 + nt * 16 + l16;
                const int slot = ((kk << 2) | quad) ^ (row & 7);
                bfr[nt] = *(short8*)&Bs[cur][row * 64 + slot * 8];
            }
#pragma unroll
            for (int mt = 0; mt < 4; mt++)
#pragma unroll
                for (int nt = 0; nt < 2; nt++) acc[mt][nt] = MFMA16(af[mt], bfr[nt], acc[mt][nt]);
        }
        __syncthreads();   // all reads of buf[cur] done; prefetch drained
    }

    // Epilogue [R5-R10 verified formulas; nt bound 2, wave n-stride 32]
#pragma unroll
    for (int nt = 0; nt < 2; nt++) {
        const int n = n0 + wc * 32 + nt * 16 + l16;
        const int seg = n >> 10;          // 0=q 1=k 2=v
        const int cn = n & 1023;
        const int h = cn >> 6, d = cn & 63;
#pragma unroll
        for (int mt = 0; mt < 4; mt++) {
#pragma unroll
            for (int r = 0; r < 4; r++) {
                const int t = m0 + wr * 64 + mt * 16 + quad * 4 + r;
                const ushort v = f2bf(acc[mt][nt][r]);
                if (seg == 0)      qb[((size_t)h * 2048 + t) * 64 + d] = v;
                else if (seg == 1) kb[((size_t)h * 2048 + t) * 64 + d] = v;
                else               vtb[((size_t)h * 64 + d) * 2048 + t] = v;
            }
        }
    }
}

// ---------------------------------------------------------------------------
// RoPE (roll variant), table-based trig.  Math identical to verified R5-R11.
// ---------------------------------------------------------------------------
__global__ __launch_bounds__(256) void rope_k(ushort* __restrict__ q,
                                              ushort* __restrict__ k,
                                              const float2* __restrict__ tab) {
    const int wid = blockIdx.x * 4 + (threadIdx.x >> 6);  // row = h*2048 + t
    const int lane = threadIdx.x & 63;
    const int t = wid & 2047;
    const float2 cs = tab[t * 32 + (lane & 31)];
    const float c = cs.x;
    const float s = cs.y;
    const size_t base = (size_t)wid * 64;

    float qv = bf2f(q[base + lane]);
    float qp = __shfl(qv, (lane + 63) & 63, 64);
    q[base + lane] = f2bf(qv * c + qp * s);

    float kv = bf2f(k[base + lane]);
    float kp = __shfl(kv, (lane + 63) & 63, 64);
    k[base + lane] = f2bf(kv * c + kp * s);
}

// ---------------------------------------------------------------------------
// Flash attention (causal), transposed form.  [R10-verified frag math]
// R12: one q-tile per block (grid 512) -> 2 blocks/CU.
// R13: no barrier between per-wave Ps write/read.
// R14: balanced qt remap (CU pairs sum to const 17 tiles).
// R18: KVBLK=64, global_load_lds(16B) staging, both-sides XOR swizzle.
// R20: K/V LDS double-buffered; tile t+1 staged before computing tile t;
//      ONE barrier per tile (prefetch drains there after full compute cover).
// ---------------------------------------------------------------------------
__global__ __launch_bounds__(256, 2) void attn_k(const ushort* __restrict__ q,
                                                 const ushort* __restrict__ k,
                                                 const ushort* __restrict__ vt,
                                                 ushort* __restrict__ y) {
    __shared__ __align__(16) ushort Ks[2][64 * 64];  // 16 KB ping-pong
    __shared__ __align__(16) ushort Vs[2][64 * 64];  // 16 KB ping-pong
    __shared__ __align__(16) ushort Ps[4][16][72];   // per-wave P^T [qrow][key]

    const int bid = blockIdx.x;
    // blocks 0..255: qt = 31,30,..,16 (16 heads each); 256..511: qt = 0,1,..,15
    const int qt = (bid < 256) ? (31 - (bid >> 4)) : ((bid >> 4) - 16);
    const int h = bid & 15;
    const int tid = threadIdx.x, w = tid >> 6, lane = tid & 63;
    const int quad = lane >> 4, l16 = lane & 15;
    const int srow = lane >> 3, sslot = lane & 7;   // staging sub-row / slot

    const int q0 = qt * 64;
    const int qrow = q0 + w * 16 + l16;

    short8 qa0, qa1;
    {
        const ushort* qp = q + ((size_t)h * 2048 + qrow) * 64 + quad * 8;
        qa0 = *(const short8*)(qp);
        qa1 = *(const short8*)(qp + 32);
    }

    floatx4 O[4];
#pragma unroll
    for (int dt = 0; dt < 4; dt++) O[dt] = (floatx4){0.f, 0.f, 0.f, 0.f};
    float M = -30000.f, L = 0.f;

    // prologue: stage tile 0 into buf 0.  global chunk cs = sslot ^ (row&7);
    // LDS stays linear (glds16 dest is wave-uniform base + lane*16).
#pragma unroll
    for (int jj = 0; jj < 2; jj++) {
        const int reg = jj * 4 + w;
        const int row = reg * 8 + srow;
        const int cs = sslot ^ (row & 7);
        glds16(&k[((size_t)h * 2048 + row) * 64 + cs * 8], &Ks[0][reg * 512]);
        glds16(&vt[((size_t)h * 64 + row) * 2048 + cs * 8], &Vs[0][reg * 512]);
    }
    __syncthreads();   // vmcnt(0) drained -> tile 0 ready

    for (int kt = 0; kt <= qt; kt++) {
        const int kbase = kt * 64;
        const int cur = kt & 1;

        // stage tile kt+1 into the other buffer; its latency hides under this
        // tile's QK^T + softmax + PV, drained at the end-of-iter barrier.
        if (kt < qt) {
            const int nb = kbase + 64;
#pragma unroll
            for (int jj = 0; jj < 2; jj++) {
                const int reg = jj * 4 + w;
                const int row = reg * 8 + srow;
                const int cs = sslot ^ (row & 7);
                glds16(&k[((size_t)h * 2048 + nb + row) * 64 + cs * 8], &Ks[cur ^ 1][reg * 512]);
                glds16(&vt[((size_t)h * 64 + row) * 2048 + nb + cs * 8], &Vs[cur ^ 1][reg * 512]);
            }
        }

        floatx4 s[4];
        __builtin_amdgcn_s_setprio(1);   // T5: QK^T MFMA cluster
#pragma unroll
        for (int nt = 0; nt < 4; nt++) {
            const int row = nt * 16 + l16;
            short8 ka0 = *(short8*)&Ks[cur][row * 64 + ((quad ^ (row & 7)) * 8)];
            short8 ka1 = *(short8*)&Ks[cur][row * 64 + (((4 | quad) ^ (row & 7)) * 8)];
            floatx4 z = (floatx4){0.f, 0.f, 0.f, 0.f};
            z = MFMA16(ka0, qa0, z);
            z = MFMA16(ka1, qa1, z);
            s[nt] = z;
        }
        __builtin_amdgcn_s_setprio(0);

        const bool diag = (kt == qt);
#pragma unroll
        for (int nt = 0; nt < 4; nt++)
#pragma unroll
            for (int r = 0; r < 4; r++) {
                float vv = s[nt][r] * 0.125f;
                if (diag) {
                    const int kidx = kbase + nt * 16 + quad * 4 + r;
                    if (kidx > qrow) vv = -30000.f;
                }
                s[nt][r] = vv;
            }

        float mx = -30000.f;
#pragma unroll
        for (int nt = 0; nt < 4; nt++)
#pragma unroll
            for (int r = 0; r < 4; r++) mx = fmaxf(mx, s[nt][r]);
        mx = fmaxf(mx, __shfl_xor(mx, 16, 64));
        mx = fmaxf(mx, __shfl_xor(mx, 32, 64));
        const float Mn = fmaxf(M, mx);
        const float alpha = __expf(M - Mn);
        float sum = 0.f;
#pragma unroll
        for (int nt = 0; nt < 4; nt++)
#pragma unroll
            for (int r = 0; r < 4; r++) {
                float pv = __expf(s[nt][r] - Mn);
                s[nt][r] = pv;
                sum += pv;
            }
        sum += __shfl_xor(sum, 16, 64);
        sum += __shfl_xor(sum, 32, 64);
        L = L * alpha + sum;
        M = Mn;
#pragma unroll
        for (int dt = 0; dt < 4; dt++) O[dt] *= alpha;

#pragma unroll
        for (int nt = 0; nt < 4; nt++) {
            ushort4 pk = make_ushort4(f2bf(s[nt][0]), f2bf(s[nt][1]),
                                      f2bf(s[nt][2]), f2bf(s[nt][3]));
            *(ushort4*)&Ps[w][l16][nt * 16 + quad * 4] = pk;
        }
        // no barrier: Ps[w] is written and read only by wave w; in-wave DS
        // ordering is enforced by the compiler's lgkmcnt tracking.

        short8 pb0 = *(short8*)&Ps[w][l16][quad * 8];
        short8 pb1 = *(short8*)&Ps[w][l16][32 + quad * 8];
        __builtin_amdgcn_s_setprio(1);   // T5: PV MFMA cluster
#pragma unroll
        for (int dt = 0; dt < 4; dt++) {
            const int row = dt * 16 + l16;
            short8 va0 = *(short8*)&Vs[cur][row * 64 + ((quad ^ (row & 7)) * 8)];
            short8 va1 = *(short8*)&Vs[cur][row * 64 + (((4 | quad) ^ (row & 7)) * 8)];
            O[dt] = MFMA16(va0, pb0, O[dt]);
            O[dt] = MFMA16(va1, pb1, O[dt]);
        }
        __builtin_amdgcn_s_setprio(0);

        __syncthreads();   // all reads of buf[cur] done; prefetch drained
    }

    const float rl = 1.0f / L;
#pragma unroll
    for (int dt = 0; dt < 4; dt++) {
        ushort4 o4 = make_ushort4(f2bf(O[dt][0] * rl), f2bf(O[dt][1] * rl),
                                  f2bf(O[dt][2] * rl), f2bf(O[dt][3] * rl));
        *(ushort4*)&y[(size_t)qrow * 1024 + h * 64 + dt * 16 + quad * 4] = o4;
    }
}

// ---------------------------------------------------------------------------
// GEMM2 (one batch): out(f32) = y[2048][1024](bf16) @ WpT^T (bf16 [1024][1024])
// R15 structure; R20: double-buffered staging, one barrier per K-step.
// ---------------------------------------------------------------------------
__global__ __launch_bounds__(256, 2) void gemm2_proj_k(const ushort* __restrict__ Y,
                                                       const ushort* __restrict__ Bt,
                                                       float* __restrict__ out) {
    __shared__ __align__(16) ushort As[2][64 * 64];   // 16 KB ping-pong
    __shared__ __align__(16) ushort Bs[2][64 * 64];   // 16 KB ping-pong
    const int tid = threadIdx.x;
    const int m0 = blockIdx.y * 64, n0 = blockIdx.x * 64;
    const int w = tid >> 6, lane = tid & 63, quad = lane >> 4, l16 = lane & 15;
    const int wr = w >> 1, wc = w & 1;
    const int K = 1024;
    const int srow = lane >> 3, sslot = lane & 7;

    floatx4 acc[2][2];
#pragma unroll
    for (int mt = 0; mt < 2; mt++)
#pragma unroll
        for (int nt = 0; nt < 2; nt++) acc[mt][nt] = (floatx4){0.f, 0.f, 0.f, 0.f};

    // prologue: stage k0=0 into buf 0
#pragma unroll
    for (int jj = 0; jj < 2; jj++) {
        const int reg = jj * 4 + w;
        const int row = reg * 8 + srow;
        const int cs = sslot ^ (row & 7);
        glds16(&Y[(size_t)(m0 + row) * K + cs * 8], &As[0][reg * 512]);
        glds16(&Bt[(size_t)(n0 + row) * K + cs * 8], &Bs[0][reg * 512]);
    }
    __syncthreads();

    for (int k0 = 0; k0 < K; k0 += 64) {
        const int cur = (k0 >> 6) & 1;
        if (k0 + 64 < K) {
            const int kn = k0 + 64;
#pragma unroll
            for (int jj = 0; jj < 2; jj++) {
                const int reg = jj * 4 + w;
                const int row = reg * 8 + srow;
                const int cs = sslot ^ (row & 7);
                glds16(&Y[(size_t)(m0 + row) * K + kn + cs * 8], &As[cur ^ 1][reg * 512]);
                glds16(&Bt[(size_t)(n0 + row) * K + kn + cs * 8], &Bs[cur ^ 1][reg * 512]);
            }
        }

#pragma unroll
        for (int kk = 0; kk < 2; kk++) {
            short8 af[2], bfr[2];
#pragma unroll
            for (int mt = 0; mt < 2; mt++) {
                const int row = wr * 32 + mt * 16 + l16;
                const int slot = ((kk << 2) | quad) ^ (row & 7);
                af[mt] = *(short8*)&As[cur][row * 64 + slot * 8];
            }
#pragma unroll
            for (int nt = 0; nt < 2; nt++) {
                const int row = wc * 32 + nt * 16 + l16;
                const int slot = ((kk << 2) | quad) ^ (row & 7);
                bfr[nt] = *(short8*)&Bs[cur][row * 64 + slot * 8];
            }
#pragma unroll
            for (int mt = 0; mt < 2; mt++)
#pragma unroll
                for (int nt = 0; nt < 2; nt++) acc[mt][nt] = MFMA16(af[mt], bfr[nt], acc[mt][nt]);
        }
        __syncthreads();
    }

#pragma unroll
    for (int mt = 0; mt < 2; mt++)
#pragma unroll
        for (int nt = 0; nt < 2; nt++) {
            const int n = n0 + wc * 32 + nt * 16 + l16;
#pragma unroll
            for (int r = 0; r < 4; r++) {
                const int m = m0 + wr * 32 + mt * 16 + quad * 4 + r;
                out[(size_t)m * 1024 + n] = acc[mt][nt][r];
            }
        }
}

// ---------------------------------------------------------------------------
extern "C" void kernel_launch(void* const* d_in, const int* in_sizes, int n_in,
                              void* d_out, int out_size, void* d_ws, size_t ws_size,
                              hipStream_t stream) {
    const float* x  = (const float*)d_in[0];   // [2,2048,1024] f32
    const float* Wa = (const float*)d_in[1];   // [1024,3072]  f32
    const float* Wp = (const float*)d_in[2];   // [1024,1024]  f32
    float* out = (float*)d_out;                // [2,2048,1024] f32

    const size_t PB = (size_t)2048 * 1024;     // per-batch elements
    ushort* qb  = (ushort*)d_ws;               // 4 MB bf16 q  [H,T,HD]
    ushort* kb  = qb + PB;                     // 4 MB bf16 k  [H,T,HD]
    ushort* vtb = kb + PB;                     // 4 MB bf16 v^T[H,HD,T]
    ushort* yb  = vtb + PB;                    // 4 MB bf16 y [T,C] / x_bf16
    ushort* wtA = (ushort*)(out + PB);         // 6 MB W_attn^T bf16 (d_out b1
                                               //  half; dead until gemm2-b1,
                                               //  which fully overwrites it)
    float2* tab = (float2*)(wtA + (size_t)3 * 1024 * 1024);
                                               // 512 KB trig table, bytes
                                               //  [14MB,14.5MB) of d_out; last
                                               //  read by rope-b1, overwritten
                                               //  only by gemm2-b1

    // W_proj^T: hoisted to stable ws tail (d_ws+16MB) when it fits; else the
    // per-batch qb-slot path (wtP regenerated each batch, over dead q).
    const bool hoistWp = ws_size >= (size_t)18 * 1024 * 1024;
    ushort* wtP_stable = yb + PB;              // d_ws + 16MB (only if hoistWp)

    tp_k<<<dim3(96, 32), 256, 0, stream>>>(Wa, wtA, 1024, 3072);
    trig_k<<<dim3(256), 256, 0, stream>>>(tab);
    if (hoistWp)
        tp_k<<<dim3(32, 32), 256, 0, stream>>>(Wp, wtP_stable, 1024, 1024);

    for (int b = 0; b < 2; b++) {
        cvt_k<<<dim3(2048), 256, 0, stream>>>(x + b * PB, yb);        // xb in yb slot
        gemm1_qkv_k<<<dim3(48, 16), 256, 0, stream>>>(yb, wtA, qb, kb, vtb);
        rope_k<<<dim3(8192), 256, 0, stream>>>(qb, kb, tab);
        attn_k<<<dim3(512), 256, 0, stream>>>(qb, kb, vtb, yb);       // y over xb
        if (hoistWp) {
            gemm2_proj_k<<<dim3(16, 32), 256, 0, stream>>>(yb, wtP_stable, out + b * PB);
        } else {
            tp_k<<<dim3(32, 32), 256, 0, stream>>>(Wp, qb, 1024, 1024);  // over dead q
            gemm2_proj_k<<<dim3(16, 32), 256, 0, stream>>>(yb, qb, out + b * PB);
        }
    }
}

// Round 12
// 252.517 us; speedup vs baseline: 1.0661x; 1.0661x over previous
//
#include <hip/hip_runtime.h>

// ---------------------------------------------------------------------------
// qkv = x@W_attn; RoPE(q,k); flash-attn; y@W_proj
// B=2, T=2048, C=1024, H=16, HD=64.  I/O fp32; internal tensors bf16.
//
// R23 == R22 == R21 byte-identical (broker down two rounds running; R21
// still unmeasured).  Third audit pass found no defect: staging XOR
// involutions hold both sides (K 8-chunk, V 16-chunk; pb[ks] keys
// ks*32+quad*8 == va chunk (ks*4+quad)*8); max live VGPR ~95 (no staging
// regs -> R17's spill mode impossible); LPT pair-sum 17 constant;
// exact-skip is bit-identical IEEE.  Submitting unchanged.
//
// R21 change log (vs measured R18=259.08 best / R20 dbuf=NULL):
//  * gemm1/gemm2: R18 single-buffer form (measured best).
//  * attn KVBLK=128: halves per-key serial-chain cost (shfl_xor, Ps
//    round-trip, M/L/alpha/rescale, barriers once per 128 keys).  Math =
//    R17-harness-verified; staging = R18-verified glds16 + both-sides XOR.
//  * exact-skip defer-max (alpha==1 path).  setprio around MFMA clusters.
// ---------------------------------------------------------------------------

typedef __attribute__((ext_vector_type(8))) short short8;   // 8 bf16 = 4 VGPRs
typedef __attribute__((ext_vector_type(4))) float floatx4;  // MFMA C/D frag

__device__ __forceinline__ ushort f2bf(float f) {
    unsigned x = __float_as_uint(f);
    x += 0x7fffu + ((x >> 16) & 1u);   // round-to-nearest-even
    return (ushort)(x >> 16);
}
__device__ __forceinline__ float bf2f(ushort u) {
    return __uint_as_float(((unsigned)u) << 16);
}

#define MFMA16(a, b, c) __builtin_amdgcn_mfma_f32_16x16x32_bf16((a), (b), (c), 0, 0, 0)

// async global->LDS, 16 bytes per lane.  LDS dest must be wave-uniform base;
// HW writes base + lane*16.  Global src is per-lane.
__device__ __forceinline__ void glds16(const ushort* g, ushort* l) {
    __builtin_amdgcn_global_load_lds(
        (const __attribute__((address_space(1))) unsigned int*)g,
        (__attribute__((address_space(3))) unsigned int*)l, 16, 0, 0);
}

// ---------------------------------------------------------------------------
// Transpose + cvt: src f32 [R][C] -> dst bf16 [C][R].  32x32 tiles via LDS.
// ---------------------------------------------------------------------------
__global__ __launch_bounds__(256) void tp_k(const float* __restrict__ src,
                                            ushort* __restrict__ dst,
                                            int R, int C) {
    __shared__ ushort t[32][34];
    const int c0 = blockIdx.x * 32, r0 = blockIdx.y * 32;
    const int tr = threadIdx.x >> 5, tc = threadIdx.x & 31;
#pragma unroll
    for (int j = 0; j < 4; j++)
        t[tr + j * 8][tc] = f2bf(src[(size_t)(r0 + tr + j * 8) * C + c0 + tc]);
    __syncthreads();
#pragma unroll
    for (int j = 0; j < 4; j++)
        dst[(size_t)(c0 + tr + j * 8) * R + r0 + tc] = t[tc][tr + j * 8];
}

// ---------------------------------------------------------------------------
// cvt: f32 -> bf16, 4 elems/thread.
// ---------------------------------------------------------------------------
__global__ __launch_bounds__(256) void cvt_k(const float* __restrict__ src,
                                             ushort* __restrict__ dst) {
    const size_t i = ((size_t)blockIdx.x * 256 + threadIdx.x) * 4;
    float4 t4 = *(const float4*)&src[i];
    *(ushort4*)&dst[i] = make_ushort4(f2bf(t4.x), f2bf(t4.y), f2bf(t4.z), f2bf(t4.w));
}

// ---------------------------------------------------------------------------
// trig table: tab[t][j] = (cos(t * 10000^(-j/32)), sin(...)), f64 math
// identical to the original in-rope computation (bit-identical results).
// ---------------------------------------------------------------------------
__global__ __launch_bounds__(256) void trig_k(float2* __restrict__ tab) {
    const int idx = blockIdx.x * 256 + threadIdx.x;   // [0, 65536)
    const int t = idx >> 5, j = idx & 31;
    const double inv = pow(10000.0, -(double)j / 32.0);
    const double ang = (double)t * inv;
    tab[idx] = make_float2((float)cos(ang), (float)sin(ang));
}

// ---------------------------------------------------------------------------
// GEMM1 (one batch): qkv = xb[2048][1024](bf16) @ WaT^T (Bt bf16 [3072][1024])
//   -> q: [H,T,HD]  k: [H,T,HD]  v^T: [H,HD,T]  (bf16)
// R15/R18 form (measured best): 128x64 tile, BK=64, glds16, swizzled LDS.
// ---------------------------------------------------------------------------
__global__ __launch_bounds__(256, 3) void gemm1_qkv_k(const ushort* __restrict__ Ab,
                                                      const ushort* __restrict__ Bt,
                                                      ushort* __restrict__ qb,
                                                      ushort* __restrict__ kb,
                                                      ushort* __restrict__ vtb) {
    __shared__ __align__(16) ushort As[128 * 64];  // 16 KB, linear+swizzled
    __shared__ __align__(16) ushort Bs[64 * 64];   // 8 KB
    const int tid = threadIdx.x;
    const int m0 = blockIdx.y * 128, n0 = blockIdx.x * 64;
    const int w = tid >> 6, lane = tid & 63, quad = lane >> 4, l16 = lane & 15;
    const int wr = w >> 1, wc = w & 1;
    const int K = 1024;
    const int srow = lane >> 3, sslot = lane & 7;  // staging sub-row / slot

    floatx4 acc[4][2];
#pragma unroll
    for (int mt = 0; mt < 4; mt++)
#pragma unroll
        for (int nt = 0; nt < 2; nt++) acc[mt][nt] = (floatx4){0.f, 0.f, 0.f, 0.f};

    for (int k0 = 0; k0 < K; k0 += 64) {
        __syncthreads();   // all waves done reading prev tile
#pragma unroll
        for (int jj = 0; jj < 4; jj++) {
            const int reg = jj * 4 + w;
            const int row = reg * 8 + srow;
            const int cs = sslot ^ (row & 7);
            glds16(&Ab[(size_t)(m0 + row) * K + k0 + cs * 8], &As[reg * 512]);
        }
#pragma unroll
        for (int jj = 0; jj < 2; jj++) {
            const int reg = jj * 4 + w;
            const int row = reg * 8 + srow;
            const int cs = sslot ^ (row & 7);
            glds16(&Bt[(size_t)(n0 + row) * K + k0 + cs * 8], &Bs[reg * 512]);
        }
        __syncthreads();   // compiler drains vmcnt(0) before barrier

#pragma unroll
        for (int kk = 0; kk < 2; kk++) {
            short8 af[4], bfr[2];
#pragma unroll
            for (int mt = 0; mt < 4; mt++) {
                const int row = wr * 64 + mt * 16 + l16;
                const int slot = ((kk << 2) | quad) ^ (row & 7);
                af[mt] = *(short8*)&As[row * 64 + slot * 8];
            }
#pragma unroll
            for (int nt = 0; nt < 2; nt++) {
                const int row = wc * 32 + nt * 16 + l16;
                const int slot = ((kk << 2) | quad) ^ (row & 7);
                bfr[nt] = *(short8*)&Bs[row * 64 + slot * 8];
            }
#pragma unroll
            for (int mt = 0; mt < 4; mt++)
#pragma unroll
                for (int nt = 0; nt < 2; nt++) acc[mt][nt] = MFMA16(af[mt], bfr[nt], acc[mt][nt]);
        }
    }

    // Epilogue [R5-R10 verified formulas; nt bound 2, wave n-stride 32]
#pragma unroll
    for (int nt = 0; nt < 2; nt++) {
        const int n = n0 + wc * 32 + nt * 16 + l16;
        const int seg = n >> 10;          // 0=q 1=k 2=v
        const int cn = n & 1023;
        const int h = cn >> 6, d = cn & 63;
#pragma unroll
        for (int mt = 0; mt < 4; mt++) {
#pragma unroll
            for (int r = 0; r < 4; r++) {
                const int t = m0 + wr * 64 + mt * 16 + quad * 4 + r;
                const ushort v = f2bf(acc[mt][nt][r]);
                if (seg == 0)      qb[((size_t)h * 2048 + t) * 64 + d] = v;
                else if (seg == 1) kb[((size_t)h * 2048 + t) * 64 + d] = v;
                else               vtb[((size_t)h * 64 + d) * 2048 + t] = v;
            }
        }
    }
}

// ---------------------------------------------------------------------------
// RoPE (roll variant), table-based trig.  Math identical to verified R5-R11.
// ---------------------------------------------------------------------------
__global__ __launch_bounds__(256) void rope_k(ushort* __restrict__ q,
                                              ushort* __restrict__ k,
                                              const float2* __restrict__ tab) {
    const int wid = blockIdx.x * 4 + (threadIdx.x >> 6);  // row = h*2048 + t
    const int lane = threadIdx.x & 63;
    const int t = wid & 2047;
    const float2 cs = tab[t * 32 + (lane & 31)];
    const float c = cs.x;
    const float s = cs.y;
    const size_t base = (size_t)wid * 64;

    float qv = bf2f(q[base + lane]);
    float qp = __shfl(qv, (lane + 63) & 63, 64);
    q[base + lane] = f2bf(qv * c + qp * s);

    float kv = bf2f(k[base + lane]);
    float kp = __shfl(kv, (lane + 63) & 63, 64);
    k[base + lane] = f2bf(kv * c + kp * s);
}

// ---------------------------------------------------------------------------
// Flash attention (causal), transposed form.
// R12: one q-tile per block (grid 512) -> 2 blocks/CU.
// R13: no barrier between per-wave Ps write/read.
// R14: balanced qt remap (CU pairs sum to const 17 KVBLK=128 tiles).
// R21: KVBLK=128 (R17-verified math: nkt=(qt>>1)+1, unconditional mask) with
//      R18-verified glds16 staging (no staging regs -> no scratch);
//      exact-skip defer-max (alpha==1 path, bit-identical).
// ---------------------------------------------------------------------------
__global__ __launch_bounds__(256, 2) void attn_k(const ushort* __restrict__ q,
                                                 const ushort* __restrict__ k,
                                                 const ushort* __restrict__ vt,
                                                 ushort* __restrict__ y) {
    __shared__ __align__(16) ushort Ks[128 * 64];   // [key][d]  16 KB swz
    __shared__ __align__(16) ushort Vs[64 * 128];   // [d][key]  16 KB swz
    __shared__ __align__(16) ushort Ps[4][16][136]; // per-wave P^T [qrow][key]

    const int bid = blockIdx.x;
    // blocks 0..255: qt = 31,30,..,16 (16 heads each); 256..511: qt = 0,1,..,15
    const int qt = (bid < 256) ? (31 - (bid >> 4)) : ((bid >> 4) - 16);
    const int h = bid & 15;
    const int tid = threadIdx.x, w = tid >> 6, lane = tid & 63;
    const int quad = lane >> 4, l16 = lane & 15;
    const int srow8 = lane >> 3, sslot8 = lane & 7;   // K staging (8 rows/KB)
    const int srow4 = lane >> 4, sslot16 = lane & 15; // V staging (4 rows/KB)

    const int q0 = qt * 64;
    const int qrow = q0 + w * 16 + l16;
    const int nkt = (qt >> 1) + 1;     // 128-key tiles; trailing keys masked

    short8 qa0, qa1;
    {
        const ushort* qp = q + ((size_t)h * 2048 + qrow) * 64 + quad * 8;
        qa0 = *(const short8*)(qp);
        qa1 = *(const short8*)(qp + 32);
    }

    floatx4 O[4];
#pragma unroll
    for (int dt = 0; dt < 4; dt++) O[dt] = (floatx4){0.f, 0.f, 0.f, 0.f};
    float M = -30000.f, L = 0.f;

    for (int kt2 = 0; kt2 < nkt; kt2++) {
        const int kbase = kt2 * 128;
        __syncthreads();   // all waves done reading prev tile's LDS
        // K: 128 rows x 64 (128B rows, 8 chunks), 16 regions of 8 rows.
#pragma unroll
        for (int jj = 0; jj < 4; jj++) {
            const int reg = jj * 4 + w;
            const int row = reg * 8 + srow8;
            const int cs = sslot8 ^ (row & 7);
            glds16(&k[((size_t)h * 2048 + kbase + row) * 64 + cs * 8], &Ks[reg * 512]);
        }
        // V^T: 64 rows x 128 (256B rows, 16 chunks), 16 regions of 4 rows.
#pragma unroll
        for (int jj = 0; jj < 4; jj++) {
            const int reg = jj * 4 + w;
            const int row = reg * 4 + srow4;
            const int cs = sslot16 ^ (row & 15);
            glds16(&vt[((size_t)h * 64 + row) * 2048 + kbase + cs * 8], &Vs[reg * 512]);
        }
        __syncthreads();   // staging complete (vmcnt(0) drained at barrier)

        floatx4 s[8];
        __builtin_amdgcn_s_setprio(1);   // T5: QK^T MFMA cluster
#pragma unroll
        for (int nt = 0; nt < 8; nt++) {
            const int row = nt * 16 + l16;
            short8 ka0 = *(short8*)&Ks[row * 64 + ((quad ^ (row & 7)) * 8)];
            short8 ka1 = *(short8*)&Ks[row * 64 + (((4 | quad) ^ (row & 7)) * 8)];
            floatx4 z = (floatx4){0.f, 0.f, 0.f, 0.f};
            z = MFMA16(ka0, qa0, z);
            z = MFMA16(ka1, qa1, z);
            s[nt] = z;
        }
        __builtin_amdgcn_s_setprio(0);

        // scale + unconditional causal mask  [R17-verified]
#pragma unroll
        for (int nt = 0; nt < 8; nt++)
#pragma unroll
            for (int r = 0; r < 4; r++) {
                const int kidx = kbase + nt * 16 + quad * 4 + r;
                const float vv = s[nt][r] * 0.125f;
                s[nt][r] = (kidx > qrow) ? -30000.f : vv;
            }

        // tree max over 32 values (max is exactly associative)
        float mr[8];
#pragma unroll
        for (int nt = 0; nt < 8; nt++)
            mr[nt] = fmaxf(fmaxf(s[nt][0], s[nt][1]), fmaxf(s[nt][2], s[nt][3]));
        float mx = fmaxf(fmaxf(fmaxf(mr[0], mr[1]), fmaxf(mr[2], mr[3])),
                         fmaxf(fmaxf(mr[4], mr[5]), fmaxf(mr[6], mr[7])));
        mx = fmaxf(mx, __shfl_xor(mx, 16, 64));
        mx = fmaxf(mx, __shfl_xor(mx, 32, 64));

        // exact-skip defer-max: if no lane's max grew, Mn==M and alpha==1
        // exactly -> skipping rescale is bit-identical.
        if (!__all(mx <= M)) {
            const float Mn = fmaxf(M, mx);
            const float alpha = __expf(M - Mn);
            L *= alpha;
#pragma unroll
            for (int dt = 0; dt < 4; dt++) O[dt] *= alpha;
            M = Mn;
        }

        float sum = 0.f;
#pragma unroll
        for (int nt = 0; nt < 8; nt++)
#pragma unroll
            for (int r = 0; r < 4; r++) {
                const float pv = __expf(s[nt][r] - M);
                s[nt][r] = pv;
                sum += pv;
            }
        sum += __shfl_xor(sum, 16, 64);
        sum += __shfl_xor(sum, 32, 64);
        L += sum;

#pragma unroll
        for (int nt = 0; nt < 8; nt++) {
            ushort4 pk = make_ushort4(f2bf(s[nt][0]), f2bf(s[nt][1]),
                                      f2bf(s[nt][2]), f2bf(s[nt][3]));
            *(ushort4*)&Ps[w][l16][nt * 16 + quad * 4] = pk;
        }
        // no barrier: Ps[w] is written and read only by wave w; in-wave DS
        // ordering is enforced by the compiler's lgkmcnt tracking.

        short8 pb[4];
#pragma unroll
        for (int ks = 0; ks < 4; ks++)
            pb[ks] = *(short8*)&Ps[w][l16][ks * 32 + quad * 8];
        __builtin_amdgcn_s_setprio(1);   // T5: PV MFMA cluster
#pragma unroll
        for (int dt = 0; dt < 4; dt++) {
            const int row = dt * 16 + l16;
#pragma unroll
            for (int ks = 0; ks < 4; ks++) {
                const int cc = (ks * 4 + quad) ^ (row & 15);
                short8 va = *(short8*)&Vs[row * 128 + cc * 8];
                O[dt] = MFMA16(va, pb[ks], O[dt]);
            }
        }
        __builtin_amdgcn_s_setprio(0);
    }

    const float rl = 1.0f / L;
#pragma unroll
    for (int dt = 0; dt < 4; dt++) {
        ushort4 o4 = make_ushort4(f2bf(O[dt][0] * rl), f2bf(O[dt][1] * rl),
                                  f2bf(O[dt][2] * rl), f2bf(O[dt][3] * rl));
        *(ushort4*)&y[(size_t)qrow * 1024 + h * 64 + dt * 16 + quad * 4] = o4;
    }
}

// ---------------------------------------------------------------------------
// GEMM2 (one batch): out(f32) = y[2048][1024](bf16) @ WpT^T (bf16 [1024][1024])
// R15/R18 form (measured best): 64x64 tile, BK=64, glds16, swizzled LDS.
// ---------------------------------------------------------------------------
__global__ __launch_bounds__(256, 2) void gemm2_proj_k(const ushort* __restrict__ Y,
                                                       const ushort* __restrict__ Bt,
                                                       float* __restrict__ out) {
    __shared__ __align__(16) ushort As[64 * 64];   // 8 KB, linear+swizzled
    __shared__ __align__(16) ushort Bs[64 * 64];   // 8 KB
    const int tid = threadIdx.x;
    const int m0 = blockIdx.y * 64, n0 = blockIdx.x * 64;
    const int w = tid >> 6, lane = tid & 63, quad = lane >> 4, l16 = lane & 15;
    const int wr = w >> 1, wc = w & 1;
    const int K = 1024;
    const int srow = lane >> 3, sslot = lane & 7;

    floatx4 acc[2][2];
#pragma unroll
    for (int mt = 0; mt < 2; mt++)
#pragma unroll
        for (int nt = 0; nt < 2; nt++) acc[mt][nt] = (floatx4){0.f, 0.f, 0.f, 0.f};

    for (int k0 = 0; k0 < K; k0 += 64) {
        __syncthreads();
#pragma unroll
        for (int jj = 0; jj < 2; jj++) {
            const int reg = jj * 4 + w;
            const int row = reg * 8 + srow;
            const int cs = sslot ^ (row & 7);
            glds16(&Y[(size_t)(m0 + row) * K + k0 + cs * 8], &As[reg * 512]);
            glds16(&Bt[(size_t)(n0 + row) * K + k0 + cs * 8], &Bs[reg * 512]);
        }
        __syncthreads();

#pragma unroll
        for (int kk = 0; kk < 2; kk++) {
            short8 af[2], bfr[2];
#pragma unroll
            for (int mt = 0; mt < 2; mt++) {
                const int row = wr * 32 + mt * 16 + l16;
                const int slot = ((kk << 2) | quad) ^ (row & 7);
                af[mt] = *(short8*)&As[row * 64 + slot * 8];
            }
#pragma unroll
            for (int nt = 0; nt < 2; nt++) {
                const int row = wc * 32 + nt * 16 + l16;
                const int slot = ((kk << 2) | quad) ^ (row & 7);
                bfr[nt] = *(short8*)&Bs[row * 64 + slot * 8];
            }
#pragma unroll
            for (int mt = 0; mt < 2; mt++)
#pragma unroll
                for (int nt = 0; nt < 2; nt++) acc[mt][nt] = MFMA16(af[mt], bfr[nt], acc[mt][nt]);
        }
    }

#pragma unroll
    for (int mt = 0; mt < 2; mt++)
#pragma unroll
        for (int nt = 0; nt < 2; nt++) {
            const int n = n0 + wc * 32 + nt * 16 + l16;
#pragma unroll
            for (int r = 0; r < 4; r++) {
                const int m = m0 + wr * 32 + mt * 16 + quad * 4 + r;
                out[(size_t)m * 1024 + n] = acc[mt][nt][r];
            }
        }
}

// ---------------------------------------------------------------------------
extern "C" void kernel_launch(void* const* d_in, const int* in_sizes, int n_in,
                              void* d_out, int out_size, void* d_ws, size_t ws_size,
                              hipStream_t stream) {
    const float* x  = (const float*)d_in[0];   // [2,2048,1024] f32
    const float* Wa = (const float*)d_in[1];   // [1024,3072]  f32
    const float* Wp = (const float*)d_in[2];   // [1024,1024]  f32
    float* out = (float*)d_out;                // [2,2048,1024] f32

    const size_t PB = (size_t)2048 * 1024;     // per-batch elements
    ushort* qb  = (ushort*)d_ws;               // 4 MB bf16 q  [H,T,HD]
    ushort* kb  = qb + PB;                     // 4 MB bf16 k  [H,T,HD]
    ushort* vtb = kb + PB;                     // 4 MB bf16 v^T[H,HD,T]
    ushort* yb  = vtb + PB;                    // 4 MB bf16 y [T,C] / x_bf16
    ushort* wtA = (ushort*)(out + PB);         // 6 MB W_attn^T bf16 (d_out b1
                                               //  half; dead until gemm2-b1,
                                               //  which fully overwrites it)
    float2* tab = (float2*)(wtA + (size_t)3 * 1024 * 1024);
                                               // 512 KB trig table, bytes
                                               //  [14MB,14.5MB) of d_out; last
                                               //  read by rope-b1, overwritten
                                               //  only by gemm2-b1

    // W_proj^T: hoisted to stable ws tail (d_ws+16MB) when it fits; else the
    // per-batch qb-slot path (wtP regenerated each batch, over dead q).
    const bool hoistWp = ws_size >= (size_t)18 * 1024 * 1024;
    ushort* wtP_stable = yb + PB;              // d_ws + 16MB (only if hoistWp)

    tp_k<<<dim3(96, 32), 256, 0, stream>>>(Wa, wtA, 1024, 3072);
    trig_k<<<dim3(256), 256, 0, stream>>>(tab);
    if (hoistWp)
        tp_k<<<dim3(32, 32), 256, 0, stream>>>(Wp, wtP_stable, 1024, 1024);

    for (int b = 0; b < 2; b++) {
        cvt_k<<<dim3(2048), 256, 0, stream>>>(x + b * PB, yb);        // xb in yb slot
        gemm1_qkv_k<<<dim3(48, 16), 256, 0, stream>>>(yb, wtA, qb, kb, vtb);
        rope_k<<<dim3(8192), 256, 0, stream>>>(qb, kb, tab);
        attn_k<<<dim3(512), 256, 0, stream>>>(qb, kb, vtb, yb);       // y over xb
        if (hoistWp) {
            gemm2_proj_k<<<dim3(16, 32), 256, 0, stream>>>(yb, wtP_stable, out + b * PB);
        } else {
            tp_k<<<dim3(32, 32), 256, 0, stream>>>(Wp, qb, 1024, 1024);  // over dead q
            gemm2_proj_k<<<dim3(16, 32), 256, 0, stream>>>(yb, qb, out + b * PB);
        }
    }
}

// Round 13
// 212.362 us; speedup vs baseline: 1.2677x; 1.1891x over previous
//
#include <hip/hip_runtime.h>

// ---------------------------------------------------------------------------
// qkv = x@W_attn; RoPE(q,k); flash-attn; y@W_proj
// B=2, T=2048, C=1024, H=16, HD=64.  I/O fp32; internal tensors bf16.
//
// R24 (R21 measured 252.52us; all our kernels now < 43us — top-5 is harness
// memsets.  Remaining structural waste is BETWEEN kernels: 13 serial
// latency-bound launches with idle head/tails):
//  * batch-merged launches: per-batch ws buffers (34MB, gated ws_size>=36MB)
//    let both batches run in ONE launch per stage: cvt, gemm1, rope, attn,
//    gemm2 each 2x grid.  13 -> 8 launches; tails amortize; attn's 1024
//    blocks refill dynamically (better than static LPT).
//  * kernels take a batch offset from blockIdx.z (gemms) / bid>>9 (attn) —
//    degenerates to 0 under the fallback path, so the R21 per-batch loop
//    (kept verbatim for ws<36MB) uses the SAME kernels.
//  * all kernel math byte-identical to measured R21.
// ---------------------------------------------------------------------------

typedef __attribute__((ext_vector_type(8))) short short8;   // 8 bf16 = 4 VGPRs
typedef __attribute__((ext_vector_type(4))) float floatx4;  // MFMA C/D frag

__device__ __forceinline__ ushort f2bf(float f) {
    unsigned x = __float_as_uint(f);
    x += 0x7fffu + ((x >> 16) & 1u);   // round-to-nearest-even
    return (ushort)(x >> 16);
}
__device__ __forceinline__ float bf2f(ushort u) {
    return __uint_as_float(((unsigned)u) << 16);
}

#define MFMA16(a, b, c) __builtin_amdgcn_mfma_f32_16x16x32_bf16((a), (b), (c), 0, 0, 0)

// async global->LDS, 16 bytes per lane.  LDS dest must be wave-uniform base;
// HW writes base + lane*16.  Global src is per-lane.
__device__ __forceinline__ void glds16(const ushort* g, ushort* l) {
    __builtin_amdgcn_global_load_lds(
        (const __attribute__((address_space(1))) unsigned int*)g,
        (__attribute__((address_space(3))) unsigned int*)l, 16, 0, 0);
}

// ---------------------------------------------------------------------------
// Transpose + cvt: src f32 [R][C] -> dst bf16 [C][R].  32x32 tiles via LDS.
// ---------------------------------------------------------------------------
__global__ __launch_bounds__(256) void tp_k(const float* __restrict__ src,
                                            ushort* __restrict__ dst,
                                            int R, int C) {
    __shared__ ushort t[32][34];
    const int c0 = blockIdx.x * 32, r0 = blockIdx.y * 32;
    const int tr = threadIdx.x >> 5, tc = threadIdx.x & 31;
#pragma unroll
    for (int j = 0; j < 4; j++)
        t[tr + j * 8][tc] = f2bf(src[(size_t)(r0 + tr + j * 8) * C + c0 + tc]);
    __syncthreads();
#pragma unroll
    for (int j = 0; j < 4; j++)
        dst[(size_t)(c0 + tr + j * 8) * R + r0 + tc] = t[tc][tr + j * 8];
}

// ---------------------------------------------------------------------------
// cvt: f32 -> bf16, 4 elems/thread.
// ---------------------------------------------------------------------------
__global__ __launch_bounds__(256) void cvt_k(const float* __restrict__ src,
                                             ushort* __restrict__ dst) {
    const size_t i = ((size_t)blockIdx.x * 256 + threadIdx.x) * 4;
    float4 t4 = *(const float4*)&src[i];
    *(ushort4*)&dst[i] = make_ushort4(f2bf(t4.x), f2bf(t4.y), f2bf(t4.z), f2bf(t4.w));
}

// ---------------------------------------------------------------------------
// trig table: tab[t][j] = (cos(t * 10000^(-j/32)), sin(...)), f64 math
// identical to the original in-rope computation (bit-identical results).
// ---------------------------------------------------------------------------
__global__ __launch_bounds__(256) void trig_k(float2* __restrict__ tab) {
    const int idx = blockIdx.x * 256 + threadIdx.x;   // [0, 65536)
    const int t = idx >> 5, j = idx & 31;
    const double inv = pow(10000.0, -(double)j / 32.0);
    const double ang = (double)t * inv;
    tab[idx] = make_float2((float)cos(ang), (float)sin(ang));
}

// ---------------------------------------------------------------------------
// GEMM1: qkv = xb[2048][1024](bf16) @ WaT^T (Bt bf16 [3072][1024])
//   -> q: [H,T,HD]  k: [H,T,HD]  v^T: [H,HD,T]  (bf16)
// R15/R18 form (measured best): 128x64 tile, BK=64, glds16, swizzled LDS.
// R24: batch from blockIdx.z (0 under fallback launches).
// ---------------------------------------------------------------------------
__global__ __launch_bounds__(256, 3) void gemm1_qkv_k(const ushort* __restrict__ Ab,
                                                      const ushort* __restrict__ Bt,
                                                      ushort* __restrict__ qb,
                                                      ushort* __restrict__ kb,
                                                      ushort* __restrict__ vtb) {
    __shared__ __align__(16) ushort As[128 * 64];  // 16 KB, linear+swizzled
    __shared__ __align__(16) ushort Bs[64 * 64];   // 8 KB
    const size_t boff = (size_t)blockIdx.z * (2048u * 1024u);
    Ab += boff; qb += boff; kb += boff; vtb += boff;
    const int tid = threadIdx.x;
    const int m0 = blockIdx.y * 128, n0 = blockIdx.x * 64;
    const int w = tid >> 6, lane = tid & 63, quad = lane >> 4, l16 = lane & 15;
    const int wr = w >> 1, wc = w & 1;
    const int K = 1024;
    const int srow = lane >> 3, sslot = lane & 7;  // staging sub-row / slot

    floatx4 acc[4][2];
#pragma unroll
    for (int mt = 0; mt < 4; mt++)
#pragma unroll
        for (int nt = 0; nt < 2; nt++) acc[mt][nt] = (floatx4){0.f, 0.f, 0.f, 0.f};

    for (int k0 = 0; k0 < K; k0 += 64) {
        __syncthreads();   // all waves done reading prev tile
#pragma unroll
        for (int jj = 0; jj < 4; jj++) {
            const int reg = jj * 4 + w;
            const int row = reg * 8 + srow;
            const int cs = sslot ^ (row & 7);
            glds16(&Ab[(size_t)(m0 + row) * K + k0 + cs * 8], &As[reg * 512]);
        }
#pragma unroll
        for (int jj = 0; jj < 2; jj++) {
            const int reg = jj * 4 + w;
            const int row = reg * 8 + srow;
            const int cs = sslot ^ (row & 7);
            glds16(&Bt[(size_t)(n0 + row) * K + k0 + cs * 8], &Bs[reg * 512]);
        }
        __syncthreads();   // compiler drains vmcnt(0) before barrier

#pragma unroll
        for (int kk = 0; kk < 2; kk++) {
            short8 af[4], bfr[2];
#pragma unroll
            for (int mt = 0; mt < 4; mt++) {
                const int row = wr * 64 + mt * 16 + l16;
                const int slot = ((kk << 2) | quad) ^ (row & 7);
                af[mt] = *(short8*)&As[row * 64 + slot * 8];
            }
#pragma unroll
            for (int nt = 0; nt < 2; nt++) {
                const int row = wc * 32 + nt * 16 + l16;
                const int slot = ((kk << 2) | quad) ^ (row & 7);
                bfr[nt] = *(short8*)&Bs[row * 64 + slot * 8];
            }
#pragma unroll
            for (int mt = 0; mt < 4; mt++)
#pragma unroll
                for (int nt = 0; nt < 2; nt++) acc[mt][nt] = MFMA16(af[mt], bfr[nt], acc[mt][nt]);
        }
    }

    // Epilogue [R5-R10 verified formulas; nt bound 2, wave n-stride 32]
#pragma unroll
    for (int nt = 0; nt < 2; nt++) {
        const int n = n0 + wc * 32 + nt * 16 + l16;
        const int seg = n >> 10;          // 0=q 1=k 2=v
        const int cn = n & 1023;
        const int h = cn >> 6, d = cn & 63;
#pragma unroll
        for (int mt = 0; mt < 4; mt++) {
#pragma unroll
            for (int r = 0; r < 4; r++) {
                const int t = m0 + wr * 64 + mt * 16 + quad * 4 + r;
                const ushort v = f2bf(acc[mt][nt][r]);
                if (seg == 0)      qb[((size_t)h * 2048 + t) * 64 + d] = v;
                else if (seg == 1) kb[((size_t)h * 2048 + t) * 64 + d] = v;
                else               vtb[((size_t)h * 64 + d) * 2048 + t] = v;
            }
        }
    }
}

// ---------------------------------------------------------------------------
// RoPE (roll variant), table-based trig.  Math identical to verified R5-R11.
// Row index spans batches naturally (row = (b*16+h)*2048 + t; t = wid&2047).
// ---------------------------------------------------------------------------
__global__ __launch_bounds__(256) void rope_k(ushort* __restrict__ q,
                                              ushort* __restrict__ k,
                                              const float2* __restrict__ tab) {
    const int wid = blockIdx.x * 4 + (threadIdx.x >> 6);  // row
    const int lane = threadIdx.x & 63;
    const int t = wid & 2047;
    const float2 cs = tab[t * 32 + (lane & 31)];
    const float c = cs.x;
    const float s = cs.y;
    const size_t base = (size_t)wid * 64;

    float qv = bf2f(q[base + lane]);
    float qp = __shfl(qv, (lane + 63) & 63, 64);
    q[base + lane] = f2bf(qv * c + qp * s);

    float kv = bf2f(k[base + lane]);
    float kp = __shfl(kv, (lane + 63) & 63, 64);
    k[base + lane] = f2bf(kv * c + kp * s);
}

// ---------------------------------------------------------------------------
// Flash attention (causal), transposed form.
// R12: one q-tile per block -> 2 blocks/CU.
// R13: no barrier between per-wave Ps write/read.
// R14: balanced qt remap (CU pairs sum to const tiles); R24: batch = bid>>9
//      (grid 1024 merged / 512 fallback), dynamic refill over 2x blocks.
// R21: KVBLK=128 (R17-verified math) + R18-verified glds16 staging;
//      exact-skip defer-max; setprio around MFMA clusters.
// ---------------------------------------------------------------------------
__global__ __launch_bounds__(256, 2) void attn_k(const ushort* __restrict__ q,
                                                 const ushort* __restrict__ k,
                                                 const ushort* __restrict__ vt,
                                                 ushort* __restrict__ y) {
    __shared__ __align__(16) ushort Ks[128 * 64];   // [key][d]  16 KB swz
    __shared__ __align__(16) ushort Vs[64 * 128];   // [d][key]  16 KB swz
    __shared__ __align__(16) ushort Ps[4][16][136]; // per-wave P^T [qrow][key]

    const int bid = blockIdx.x;
    const int b = bid >> 9;            // batch (0 under fallback grid 512)
    const int r9 = bid & 511;
    // r9 0..255: qt = 31,30,..,16 (16 heads each); 256..511: qt = 0,1,..,15
    const int qt = (r9 < 256) ? (31 - (r9 >> 4)) : ((r9 >> 4) - 16);
    const int h = r9 & 15;
    const size_t boff = (size_t)b * (2048u * 1024u);
    q += boff; k += boff; vt += boff; y += boff;
    const int tid = threadIdx.x, w = tid >> 6, lane = tid & 63;
    const int quad = lane >> 4, l16 = lane & 15;
    const int srow8 = lane >> 3, sslot8 = lane & 7;   // K staging (8 rows/KB)
    const int srow4 = lane >> 4, sslot16 = lane & 15; // V staging (4 rows/KB)

    const int q0 = qt * 64;
    const int qrow = q0 + w * 16 + l16;
    const int nkt = (qt >> 1) + 1;     // 128-key tiles; trailing keys masked

    short8 qa0, qa1;
    {
        const ushort* qp = q + ((size_t)h * 2048 + qrow) * 64 + quad * 8;
        qa0 = *(const short8*)(qp);
        qa1 = *(const short8*)(qp + 32);
    }

    floatx4 O[4];
#pragma unroll
    for (int dt = 0; dt < 4; dt++) O[dt] = (floatx4){0.f, 0.f, 0.f, 0.f};
    float M = -30000.f, L = 0.f;

    for (int kt2 = 0; kt2 < nkt; kt2++) {
        const int kbase = kt2 * 128;
        __syncthreads();   // all waves done reading prev tile's LDS
        // K: 128 rows x 64 (128B rows, 8 chunks), 16 regions of 8 rows.
#pragma unroll
        for (int jj = 0; jj < 4; jj++) {
            const int reg = jj * 4 + w;
            const int row = reg * 8 + srow8;
            const int cs = sslot8 ^ (row & 7);
            glds16(&k[((size_t)h * 2048 + kbase + row) * 64 + cs * 8], &Ks[reg * 512]);
        }
        // V^T: 64 rows x 128 (256B rows, 16 chunks), 16 regions of 4 rows.
#pragma unroll
        for (int jj = 0; jj < 4; jj++) {
            const int reg = jj * 4 + w;
            const int row = reg * 4 + srow4;
            const int cs = sslot16 ^ (row & 15);
            glds16(&vt[((size_t)h * 64 + row) * 2048 + kbase + cs * 8], &Vs[reg * 512]);
        }
        __syncthreads();   // staging complete (vmcnt(0) drained at barrier)

        floatx4 s[8];
        __builtin_amdgcn_s_setprio(1);   // T5: QK^T MFMA cluster
#pragma unroll
        for (int nt = 0; nt < 8; nt++) {
            const int row = nt * 16 + l16;
            short8 ka0 = *(short8*)&Ks[row * 64 + ((quad ^ (row & 7)) * 8)];
            short8 ka1 = *(short8*)&Ks[row * 64 + (((4 | quad) ^ (row & 7)) * 8)];
            floatx4 z = (floatx4){0.f, 0.f, 0.f, 0.f};
            z = MFMA16(ka0, qa0, z);
            z = MFMA16(ka1, qa1, z);
            s[nt] = z;
        }
        __builtin_amdgcn_s_setprio(0);

        // scale + unconditional causal mask  [R17-verified]
#pragma unroll
        for (int nt = 0; nt < 8; nt++)
#pragma unroll
            for (int r = 0; r < 4; r++) {
                const int kidx = kbase + nt * 16 + quad * 4 + r;
                const float vv = s[nt][r] * 0.125f;
                s[nt][r] = (kidx > qrow) ? -30000.f : vv;
            }

        // tree max over 32 values (max is exactly associative)
        float mr[8];
#pragma unroll
        for (int nt = 0; nt < 8; nt++)
            mr[nt] = fmaxf(fmaxf(s[nt][0], s[nt][1]), fmaxf(s[nt][2], s[nt][3]));
        float mx = fmaxf(fmaxf(fmaxf(mr[0], mr[1]), fmaxf(mr[2], mr[3])),
                         fmaxf(fmaxf(mr[4], mr[5]), fmaxf(mr[6], mr[7])));
        mx = fmaxf(mx, __shfl_xor(mx, 16, 64));
        mx = fmaxf(mx, __shfl_xor(mx, 32, 64));

        // exact-skip defer-max: if no lane's max grew, Mn==M and alpha==1
        // exactly -> skipping rescale is bit-identical.
        if (!__all(mx <= M)) {
            const float Mn = fmaxf(M, mx);
            const float alpha = __expf(M - Mn);
            L *= alpha;
#pragma unroll
            for (int dt = 0; dt < 4; dt++) O[dt] *= alpha;
            M = Mn;
        }

        float sum = 0.f;
#pragma unroll
        for (int nt = 0; nt < 8; nt++)
#pragma unroll
            for (int r = 0; r < 4; r++) {
                const float pv = __expf(s[nt][r] - M);
                s[nt][r] = pv;
                sum += pv;
            }
        sum += __shfl_xor(sum, 16, 64);
        sum += __shfl_xor(sum, 32, 64);
        L += sum;

#pragma unroll
        for (int nt = 0; nt < 8; nt++) {
            ushort4 pk = make_ushort4(f2bf(s[nt][0]), f2bf(s[nt][1]),
                                      f2bf(s[nt][2]), f2bf(s[nt][3]));
            *(ushort4*)&Ps[w][l16][nt * 16 + quad * 4] = pk;
        }
        // no barrier: Ps[w] is written and read only by wave w; in-wave DS
        // ordering is enforced by the compiler's lgkmcnt tracking.

        short8 pb[4];
#pragma unroll
        for (int ks = 0; ks < 4; ks++)
            pb[ks] = *(short8*)&Ps[w][l16][ks * 32 + quad * 8];
        __builtin_amdgcn_s_setprio(1);   // T5: PV MFMA cluster
#pragma unroll
        for (int dt = 0; dt < 4; dt++) {
            const int row = dt * 16 + l16;
#pragma unroll
            for (int ks = 0; ks < 4; ks++) {
                const int cc = (ks * 4 + quad) ^ (row & 15);
                short8 va = *(short8*)&Vs[row * 128 + cc * 8];
                O[dt] = MFMA16(va, pb[ks], O[dt]);
            }
        }
        __builtin_amdgcn_s_setprio(0);
    }

    const float rl = 1.0f / L;
#pragma unroll
    for (int dt = 0; dt < 4; dt++) {
        ushort4 o4 = make_ushort4(f2bf(O[dt][0] * rl), f2bf(O[dt][1] * rl),
                                  f2bf(O[dt][2] * rl), f2bf(O[dt][3] * rl));
        *(ushort4*)&y[(size_t)qrow * 1024 + h * 64 + dt * 16 + quad * 4] = o4;
    }
}

// ---------------------------------------------------------------------------
// GEMM2: out(f32) = y[2048][1024](bf16) @ WpT^T (bf16 [1024][1024])
// R15/R18 form (measured best): 64x64 tile, BK=64, glds16, swizzled LDS.
// R24: batch from blockIdx.z (0 under fallback launches).
// ---------------------------------------------------------------------------
__global__ __launch_bounds__(256, 2) void gemm2_proj_k(const ushort* __restrict__ Y,
                                                       const ushort* __restrict__ Bt,
                                                       float* __restrict__ out) {
    __shared__ __align__(16) ushort As[64 * 64];   // 8 KB, linear+swizzled
    __shared__ __align__(16) ushort Bs[64 * 64];   // 8 KB
    const size_t boff = (size_t)blockIdx.z * (2048u * 1024u);
    Y += boff; out += boff;
    const int tid = threadIdx.x;
    const int m0 = blockIdx.y * 64, n0 = blockIdx.x * 64;
    const int w = tid >> 6, lane = tid & 63, quad = lane >> 4, l16 = lane & 15;
    const int wr = w >> 1, wc = w & 1;
    const int K = 1024;
    const int srow = lane >> 3, sslot = lane & 7;

    floatx4 acc[2][2];
#pragma unroll
    for (int mt = 0; mt < 2; mt++)
#pragma unroll
        for (int nt = 0; nt < 2; nt++) acc[mt][nt] = (floatx4){0.f, 0.f, 0.f, 0.f};

    for (int k0 = 0; k0 < K; k0 += 64) {
        __syncthreads();
#pragma unroll
        for (int jj = 0; jj < 2; jj++) {
            const int reg = jj * 4 + w;
            const int row = reg * 8 + srow;
            const int cs = sslot ^ (row & 7);
            glds16(&Y[(size_t)(m0 + row) * K + k0 + cs * 8], &As[reg * 512]);
            glds16(&Bt[(size_t)(n0 + row) * K + k0 + cs * 8], &Bs[reg * 512]);
        }
        __syncthreads();

#pragma unroll
        for (int kk = 0; kk < 2; kk++) {
            short8 af[2], bfr[2];
#pragma unroll
            for (int mt = 0; mt < 2; mt++) {
                const int row = wr * 32 + mt * 16 + l16;
                const int slot = ((kk << 2) | quad) ^ (row & 7);
                af[mt] = *(short8*)&As[row * 64 + slot * 8];
            }
#pragma unroll
            for (int nt = 0; nt < 2; nt++) {
                const int row = wc * 32 + nt * 16 + l16;
                const int slot = ((kk << 2) | quad) ^ (row & 7);
                bfr[nt] = *(short8*)&Bs[row * 64 + slot * 8];
            }
#pragma unroll
            for (int mt = 0; mt < 2; mt++)
#pragma unroll
                for (int nt = 0; nt < 2; nt++) acc[mt][nt] = MFMA16(af[mt], bfr[nt], acc[mt][nt]);
        }
    }

#pragma unroll
    for (int mt = 0; mt < 2; mt++)
#pragma unroll
        for (int nt = 0; nt < 2; nt++) {
            const int n = n0 + wc * 32 + nt * 16 + l16;
#pragma unroll
            for (int r = 0; r < 4; r++) {
                const int m = m0 + wr * 32 + mt * 16 + quad * 4 + r;
                out[(size_t)m * 1024 + n] = acc[mt][nt][r];
            }
        }
}

// ---------------------------------------------------------------------------
extern "C" void kernel_launch(void* const* d_in, const int* in_sizes, int n_in,
                              void* d_out, int out_size, void* d_ws, size_t ws_size,
                              hipStream_t stream) {
    const float* x  = (const float*)d_in[0];   // [2,2048,1024] f32
    const float* Wa = (const float*)d_in[1];   // [1024,3072]  f32
    const float* Wp = (const float*)d_in[2];   // [1024,1024]  f32
    float* out = (float*)d_out;                // [2,2048,1024] f32

    const size_t PB = (size_t)2048 * 1024;     // per-batch elements
    ushort* wtA = (ushort*)(out + PB);         // 6 MB W_attn^T bf16 (d_out b1
                                               //  half; dead after gemm1, and
                                               //  gemm2-b1 fully overwrites it)
    float2* tab = (float2*)(wtA + (size_t)3 * 1024 * 1024);
                                               // 512 KB trig table (d_out b1
                                               //  tail; dead after rope)

    if (ws_size >= (size_t)36 * 1024 * 1024) {
        // -------- merged-batch path: 8 launches ---------------------------
        ushort* qbA = (ushort*)d_ws;           // [2] x 4 MB  q  [b][H,T,HD]
        ushort* kbA = qbA + 2 * PB;            // [2] x 4 MB  k
        ushort* vtA = qbA + 4 * PB;            // [2] x 4 MB  v^T
        ushort* ybA = qbA + 6 * PB;            // [2] x 4 MB  x_bf16 / y
        ushort* wtP = qbA + 8 * PB;            // 2 MB  W_proj^T

        tp_k<<<dim3(96, 32), 256, 0, stream>>>(Wa, wtA, 1024, 3072);
        trig_k<<<dim3(256), 256, 0, stream>>>(tab);
        tp_k<<<dim3(32, 32), 256, 0, stream>>>(Wp, wtP, 1024, 1024);

        cvt_k<<<dim3(4096), 256, 0, stream>>>(x, ybA);
        gemm1_qkv_k<<<dim3(48, 16, 2), 256, 0, stream>>>(ybA, wtA, qbA, kbA, vtA);
        rope_k<<<dim3(16384), 256, 0, stream>>>(qbA, kbA, tab);
        attn_k<<<dim3(1024), 256, 0, stream>>>(qbA, kbA, vtA, ybA);
        gemm2_proj_k<<<dim3(16, 32, 2), 256, 0, stream>>>(ybA, wtP, out);
        return;
    }

    // -------- fallback: R21 per-batch loop (same kernels, z=1 grids) ------
    ushort* qb  = (ushort*)d_ws;               // 4 MB bf16 q
    ushort* kb  = qb + PB;                     // 4 MB bf16 k
    ushort* vtb = kb + PB;                     // 4 MB bf16 v^T
    ushort* yb  = vtb + PB;                    // 4 MB bf16 y / x_bf16
    const bool hoistWp = ws_size >= (size_t)18 * 1024 * 1024;
    ushort* wtP_stable = yb + PB;              // d_ws + 16MB (only if hoistWp)

    tp_k<<<dim3(96, 32), 256, 0, stream>>>(Wa, wtA, 1024, 3072);
    trig_k<<<dim3(256), 256, 0, stream>>>(tab);
    if (hoistWp)
        tp_k<<<dim3(32, 32), 256, 0, stream>>>(Wp, wtP_stable, 1024, 1024);

    for (int b = 0; b < 2; b++) {
        cvt_k<<<dim3(2048), 256, 0, stream>>>(x + b * PB, yb);        // xb in yb slot
        gemm1_qkv_k<<<dim3(48, 16, 1), 256, 0, stream>>>(yb, wtA, qb, kb, vtb);
        rope_k<<<dim3(8192), 256, 0, stream>>>(qb, kb, tab);
        attn_k<<<dim3(512), 256, 0, stream>>>(qb, kb, vtb, yb);       // y over xb
        if (hoistWp) {
            gemm2_proj_k<<<dim3(16, 32, 1), 256, 0, stream>>>(yb, wtP_stable, out + b * PB);
        } else {
            tp_k<<<dim3(32, 32), 256, 0, stream>>>(Wp, qb, 1024, 1024);  // over dead q
            gemm2_proj_k<<<dim3(16, 32, 1), 256, 0, stream>>>(yb, qb, out + b * PB);
        }
    }
}